// Round 1
// 205.718 us; speedup vs baseline: 1.0201x; 1.0201x over previous
//
#include <hip/hip_runtime.h>
#include <stdint.h>

#define B_SZ   2048
#define IN_SZ  1024
#define OUT_SZ 1024
#define Q_SZ   16
#define NZB    4                              // i-windows of 256

typedef __attribute__((ext_vector_type(8))) short short8;   // 8 bf16 (4 VGPRs)
typedef __attribute__((ext_vector_type(4))) float floatx4;  // MFMA accumulator
typedef __attribute__((ext_vector_type(2))) unsigned short u16x2;
typedef __attribute__((ext_vector_type(2))) short s16x2;

__device__ __forceinline__ unsigned short f32_to_bf16_rne(float f) {
    union { float f; uint32_t u; } v; v.f = f;
    uint32_t u = v.u;
    return (unsigned short)((u + 0x7FFFu + ((u >> 16) & 1u)) >> 16);
}

// packed 2x16-bit: out = (onehot has bit q) ? xv16 : 0, in 3 VALU ops:
//   t = oh << (15-q)   (v_pk_lshlrev_b16)  -- bit q lands on bit15 iff idx==q
//   m = t >>a 15       (v_pk_ashrrev_i16)  -- 0xFFFF iff sign set
//   return x & m
__device__ __forceinline__ uint32_t mask3(uint32_t xv, uint32_t ohv, unsigned short sh) {
    union { uint32_t u; u16x2 v; s16x2 s; } t;
    t.u = ohv;
    u16x2 shv; shv.x = sh; shv.y = sh;
    t.v = t.v << shv;
    s16x2 f15; f15.x = 15; f15.y = 15;
    t.s = t.s >> f15;
    return xv & t.u;
}

// ---------------- prep: fragment-linear Wf (LDS-transpose, coalesced) -------
// Same output layout as before:
// Slab S = (zb*8+xb)*64 + ih*16 + q; chunk c = (h*8+nt)*64 + L; element j:
//   o = xb*128 + nt*16 + (L&15),  i = zb*256 + ih*64 + h*32 + (L>>4)*8 + j
// Old version gathered 4KB-strided dwords (64B useful per 128B line). New:
// coalesced float4 row loads -> bf16 in padded LDS -> coalesced uint4 stores.
__global__ void k_build_wf(const float* __restrict__ W, unsigned short* __restrict__ Wf) {
    const int S = blockIdx.x;
    const int q = S & 15, ih = (S >> 4) & 3, xb = (S >> 6) & 7, zb = S >> 9;
    const int t = threadIdx.x;
    const int i0 = zb * 256 + ih * 64;
    const int o0 = xb * 128;
    __shared__ unsigned short lds[64][130];    // pad 130: both phases ~2-way banks

    // load: 64 rows x 128 floats, fully coalesced (two 512B rows per wave-instr)
#pragma unroll
    for (int it = 0; it < 8; ++it) {
        int r  = it * 8 + (t >> 5);
        int c4 = (t & 31) * 4;
        float4 v = *(const float4*)(W + ((size_t)(q * 1024 + i0 + r)) * 1024 + o0 + c4);
        unsigned short h0 = f32_to_bf16_rne(v.x), h1 = f32_to_bf16_rne(v.y);
        unsigned short h2 = f32_to_bf16_rne(v.z), h3 = f32_to_bf16_rne(v.w);
        *(uint32_t*)&lds[r][c4]     = (uint32_t)h0 | ((uint32_t)h1 << 16);
        *(uint32_t*)&lds[r][c4 + 2] = (uint32_t)h2 | ((uint32_t)h3 << 16);
    }
    __syncthreads();

    // store: transpose out of LDS, contiguous 16B per lane (coalesced uint4)
    unsigned short* dst = Wf + (size_t)S * 8192;
#pragma unroll
    for (int it = 0; it < 4; ++it) {
        int c = it * 256 + t;
        int L = c & 63;
        int hnt = c >> 6;
        int h = hnt >> 3, nt = hnt & 7;
        int ol = nt * 16 + (L & 15);
        int il = h * 32 + (L >> 4) * 8;
        unsigned short v[8];
#pragma unroll
        for (int j = 0; j < 8; ++j) v[j] = lds[il + j][ol];
        *(uint4*)(dst + (size_t)c * 8) = *(uint4*)v;
    }
}

// ---------------- fused GEMM, LDS-free, distance-2 register pipeline ---------
// Block: 128b x 128o x (i-window 256, all 16 q) -> 64 slabs. Wave: 32b x 128o.
// Ring of 4 half-slab buffers: slab s+1's halves are issued DURING slab s and
// consumed one full slab (~2 MFMA blocks) later -> ~2x the latency slack of
// the old bA/bB scheme. ~244 regs/wave, still 2 waves/SIMD (grid-capped).
__global__ __launch_bounds__(256, 2) void k_gemm(const unsigned short* __restrict__ Wf,
                                                 const float* __restrict__ x,
                                                 const int* __restrict__ idx,
                                                 float* __restrict__ P) {
    const int tid  = threadIdx.x;
    const int wave = tid >> 6, lane = tid & 63;

    // id = zb + 4*xb + 32*yb -> XCD (id%8) = zb+4*(xb&1), constant per window.
    const int id = blockIdx.x;
    const int zb = id & 3;
    const int xb = (id >> 2) & 7;
    const int yb = id >> 5;
    const int o0 = xb * 128, b0 = yb * 128, ibase = zb * 256;

    const char* wbase = (const char*)Wf + (size_t)(zb * 8 + xb) * 64 * 16384;
    const int   lofs  = lane * 16;

    const int arow = b0 + wave * 32 + (lane & 15);
    const float* xg = x + (size_t)arow * IN_SZ + ibase + (lane >> 4) * 8;
    const int*   ig = idx + (size_t)arow * IN_SZ + ibase + (lane >> 4) * 8;

    floatx4 acc[16];
#pragma unroll
    for (int i = 0; i < 16; ++i) acc[i] = (floatx4){0.f, 0.f, 0.f, 0.f};

    uint4 xr[2][2], oh[2][2];
    short8 rb0[8], rb1[8], rb2[8], rb3[8];

#define LOADB(d, s, h)                                                        \
    {   const char* p_ = wbase + (size_t)(s) * 16384 + (h) * 8192 + lofs;     \
        _Pragma("unroll")                                                     \
        for (int nt_ = 0; nt_ < 8; ++nt_)                                     \
            (d)[nt_] = *(const short8*)(p_ + nt_ * 1024);                     \
    }

#define RELOADA(ih)                                                           \
    {   int io_ = (ih) * 64;                                                  \
        _Pragma("unroll")                                                     \
        for (int mt_ = 0; mt_ < 2; ++mt_)                                     \
            _Pragma("unroll")                                                 \
            for (int hh_ = 0; hh_ < 2; ++hh_) {                               \
                const float* xp_ = xg + mt_ * 16 * IN_SZ + io_ + hh_ * 32;    \
                const int*   ip_ = ig + mt_ * 16 * IN_SZ + io_ + hh_ * 32;    \
                float a_[8]; int b_[8];                                       \
                *(float4*)(a_)     = *(const float4*)xp_;                     \
                *(float4*)(a_ + 4) = *((const float4*)xp_ + 1);               \
                *(int4*)(b_)       = *(const int4*)ip_;                       \
                *(int4*)(b_ + 4)   = *((const int4*)ip_ + 1);                 \
                unsigned short xv_[8];                                        \
                _Pragma("unroll")                                             \
                for (int j_ = 0; j_ < 8; ++j_) xv_[j_] = f32_to_bf16_rne(a_[j_]); \
                xr[mt_][hh_] = *(uint4*)xv_;                                  \
                uint32_t iw_[4];                                              \
                _Pragma("unroll")                                             \
                for (int w_ = 0; w_ < 4; ++w_)                                \
                    iw_[w_] = (1u << b_[2 * w_]) | ((1u << b_[2 * w_ + 1]) << 16); \
                oh[mt_][hh_] = *(uint4*)iw_;                                  \
            }                                                                 \
    }

#define MASKS(hh)                                                             \
        _Pragma("unroll")                                                     \
        for (int mt_ = 0; mt_ < 2; ++mt_) {                                   \
            aF[mt_].u.x = mask3(xr[mt_][hh].x, oh[mt_][hh].x, sh_);           \
            aF[mt_].u.y = mask3(xr[mt_][hh].y, oh[mt_][hh].y, sh_);           \
            aF[mt_].u.z = mask3(xr[mt_][hh].z, oh[mt_][hh].z, sh_);           \
            aF[mt_].u.w = mask3(xr[mt_][hh].w, oh[mt_][hh].w, sh_);           \
        }

// One slab (K=64 for one q): consume (Bc0,Bc1) = slab s, prefetch (Bn0,Bn1) =
// slab s+1. Each prefetch is issued a full slab before its first consumer.
#define SLAB(s_, Bc0, Bc1, Bn0, Bn1)                                          \
    {   if ((s_) && (((s_) & 15) == 0)) RELOADA((s_) >> 4);                   \
        if ((s_) < 63) LOADB(Bn0, (s_) + 1, 0);                               \
        const unsigned short sh_ = (unsigned short)(15 - ((s_) & 15));        \
        union { uint4 u; short8 s8; } aF[2];                                  \
        MASKS(0);                                                             \
        _Pragma("unroll")                                                     \
        for (int mt_ = 0; mt_ < 2; ++mt_)                                     \
            _Pragma("unroll")                                                 \
            for (int nt_ = 0; nt_ < 8; ++nt_)                                 \
                acc[mt_ * 8 + nt_] = __builtin_amdgcn_mfma_f32_16x16x32_bf16( \
                    aF[mt_].s8, (Bc0)[nt_], acc[mt_ * 8 + nt_], 0, 0, 0);     \
        if ((s_) < 63) LOADB(Bn1, (s_) + 1, 1);                               \
        MASKS(1);                                                             \
        _Pragma("unroll")                                                     \
        for (int mt_ = 0; mt_ < 2; ++mt_)                                     \
            _Pragma("unroll")                                                 \
            for (int nt_ = 0; nt_ < 8; ++nt_)                                 \
                acc[mt_ * 8 + nt_] = __builtin_amdgcn_mfma_f32_16x16x32_bf16( \
                    aF[mt_].s8, (Bc1)[nt_], acc[mt_ * 8 + nt_], 0, 0, 0);     \
    }

    RELOADA(0);
    LOADB(rb0, 0, 0);
    LOADB(rb1, 0, 1);

#pragma unroll 1
    for (int g = 0; g < 32; ++g) {
        SLAB(2 * g,     rb0, rb1, rb2, rb3);
        SLAB(2 * g + 1, rb2, rb3, rb0, rb1);
    }

    // epilogue: plain stores to private partial buffer (C/D: col=lane&15 -> o,
    // row=(lane>>4)*4+e -> b). No atomics anywhere.
    float* Pz = P + (size_t)zb * (B_SZ * OUT_SZ);
    int cn = lane & 15, rq = lane >> 4;
#pragma unroll
    for (int mt = 0; mt < 2; ++mt)
#pragma unroll
        for (int nt = 0; nt < 8; ++nt) {
            int bb = b0 + wave * 32 + mt * 16 + rq * 4;
            int oo = o0 + nt * 16 + cn;
#pragma unroll
            for (int e = 0; e < 4; ++e)
                Pz[(size_t)(bb + e) * OUT_SZ + oo] = acc[mt * 8 + nt][e];
        }
#undef LOADB
#undef RELOADA
#undef MASKS
#undef SLAB
}

// ---------------- reduce: out = bias + sum_z P[z] ----------------
__global__ void k_reduce(const float* __restrict__ P, const float* __restrict__ bias,
                         float* __restrict__ out) {
    int t = blockIdx.x * 256 + threadIdx.x;    // float4 index, 524288 total
    const float4* b4 = (const float4*)bias;
    float4 a = b4[t & 255];
#pragma unroll
    for (int z = 0; z < NZB; ++z) {
        float4 v = ((const float4*)P)[(size_t)z * (B_SZ * OUT_SZ / 4) + t];
        a.x += v.x; a.y += v.y; a.z += v.z; a.w += v.w;
    }
    ((float4*)out)[t] = a;
}

// ---------------- fallback (ws too small): exact fp32 gather ----------------
__global__ void k_naive(const float* __restrict__ x, const int* __restrict__ idx,
                        const float* __restrict__ W, const float* __restrict__ bias,
                        float* __restrict__ out) {
    int b = blockIdx.x;
    int o = threadIdx.x * 4;
    float4 acc = *(const float4*)(bias + o);
    const float* xr = x + (size_t)b * IN_SZ;
    const int*   ir = idx + (size_t)b * IN_SZ;
    for (int i = 0; i < IN_SZ; ++i) {
        float xv = xr[i];
        int q = ir[i];
        float4 w4 = *(const float4*)(W + ((size_t)q * IN_SZ + i) * OUT_SZ + o);
        acc.x += xv * w4.x; acc.y += xv * w4.y;
        acc.z += xv * w4.z; acc.w += xv * w4.w;
    }
    *(float4*)(out + (size_t)b * OUT_SZ + o) = acc;
}

extern "C" void kernel_launch(void* const* d_in, const int* in_sizes, int n_in,
                              void* d_out, int out_size, void* d_ws, size_t ws_size,
                              hipStream_t stream) {
    const float* x    = (const float*)d_in[0];
    const int*   idx  = (const int*)d_in[1];
    const float* W    = (const float*)d_in[2];
    const float* bias = (const float*)d_in[3];
    float* out = (float*)d_out;

    const size_t wf_bytes = (size_t)2048 * 16384;                 // 32 MB frag-linear W
    const size_t p_bytes  = (size_t)NZB * B_SZ * OUT_SZ * 4;      // 32 MB partials
    if (ws_size < wf_bytes + p_bytes) {
        k_naive<<<dim3(B_SZ), dim3(256), 0, stream>>>(x, idx, W, bias, out);
        return;
    }
    unsigned short* Wf = (unsigned short*)d_ws;
    float* P = (float*)((char*)d_ws + wf_bytes);

    k_build_wf<<<dim3(2048), dim3(256), 0, stream>>>(W, Wf);
    k_gemm<<<dim3(NZB * 8 * (B_SZ / 128)), dim3(256), 0, stream>>>(Wf, x, idx, P);
    k_reduce<<<dim3(2048), dim3(256), 0, stream>>>(P, bias, out);
}

// Round 2
// 192.143 us; speedup vs baseline: 1.0921x; 1.0707x over previous
//
#include <hip/hip_runtime.h>
#include <stdint.h>

#define B_SZ   2048
#define IN_SZ  1024
#define OUT_SZ 1024
#define Q_SZ   16
#define NZB    4                              // i-windows of 256

typedef __attribute__((ext_vector_type(8))) short short8;   // 8 bf16 (4 VGPRs)
typedef __attribute__((ext_vector_type(4))) float floatx4;  // MFMA accumulator
typedef __attribute__((ext_vector_type(2))) unsigned short u16x2;
typedef __attribute__((ext_vector_type(2))) short s16x2;

__device__ __forceinline__ unsigned short f32_to_bf16_rne(float f) {
    union { float f; uint32_t u; } v; v.f = f;
    uint32_t u = v.u;
    return (unsigned short)((u + 0x7FFFu + ((u >> 16) & 1u)) >> 16);
}

// packed 2x16-bit: out = (onehot has bit q) ? xv16 : 0, in 3 VALU ops.
__device__ __forceinline__ uint32_t mask3(uint32_t xv, uint32_t ohv, unsigned short sh) {
    union { uint32_t u; u16x2 v; s16x2 s; } t;
    t.u = ohv;
    u16x2 shv; shv.x = sh; shv.y = sh;
    t.v = t.v << shv;
    s16x2 f15; f15.x = 15; f15.y = 15;
    t.s = t.s >> f15;
    return xv & t.u;
}

// async global->LDS, 16B per lane, linear (wave-uniform base + lane*16)
__device__ __forceinline__ void gload_lds16(const void* g, void* l) {
    __builtin_amdgcn_global_load_lds(
        (const __attribute__((address_space(1))) unsigned int*)g,
        (__attribute__((address_space(3))) unsigned int*)l, 16, 0, 0);
}

// ---------------- prep: fragment-linear Wf (LDS-transpose, coalesced) -------
// Slab S = (zb*8+xb)*64 + ih*16 + q; chunk c = (h*8+nt)*64 + L; element j:
//   o = xb*128 + nt*16 + (L&15),  i = zb*256 + ih*64 + h*32 + (L>>4)*8 + j
__global__ void k_build_wf(const float* __restrict__ W, unsigned short* __restrict__ Wf) {
    const int S = blockIdx.x;
    const int q = S & 15, ih = (S >> 4) & 3, xb = (S >> 6) & 7, zb = S >> 9;
    const int t = threadIdx.x;
    const int i0 = zb * 256 + ih * 64;
    const int o0 = xb * 128;
    __shared__ unsigned short lds[64][130];    // pad 130: both phases ~2-way banks

#pragma unroll
    for (int it = 0; it < 8; ++it) {
        int r  = it * 8 + (t >> 5);
        int c4 = (t & 31) * 4;
        float4 v = *(const float4*)(W + ((size_t)(q * 1024 + i0 + r)) * 1024 + o0 + c4);
        unsigned short h0 = f32_to_bf16_rne(v.x), h1 = f32_to_bf16_rne(v.y);
        unsigned short h2 = f32_to_bf16_rne(v.z), h3 = f32_to_bf16_rne(v.w);
        *(uint32_t*)&lds[r][c4]     = (uint32_t)h0 | ((uint32_t)h1 << 16);
        *(uint32_t*)&lds[r][c4 + 2] = (uint32_t)h2 | ((uint32_t)h3 << 16);
    }
    __syncthreads();

    unsigned short* dst = Wf + (size_t)S * 8192;
#pragma unroll
    for (int it = 0; it < 4; ++it) {
        int c = it * 256 + t;
        int L = c & 63;
        int hnt = c >> 6;
        int h = hnt >> 3, nt = hnt & 7;
        int ol = nt * 16 + (L & 15);
        int il = h * 32 + (L >> 4) * 8;
        unsigned short v[8];
#pragma unroll
        for (int j = 0; j < 8; ++j) v[j] = lds[il + j][ol];
        *(uint4*)(dst + (size_t)c * 8) = *(uint4*)v;
    }
}

// ---------------- fused GEMM: LDS-staged B (shared across 4 waves) -----------
// Block: 128b x 128o x (i-window 256, all 16 q) -> 64 slabs. Wave: 32b x 128o.
// B slab (16KB) staged ONCE per block via global_load_lds (linear layout, no
// swizzle needed), double-buffered; all 4 waves ds_read_b128 the same frags.
// Cuts L1 B-traffic 4x (the R0/R1 wall: 8 waves x 16KB/slab through a
// ~32-64 B/cy L1). New cap: LDS ~1900cy vs MFMA 1242cy per slab per CU.
__global__ __launch_bounds__(256, 2) void k_gemm(const unsigned short* __restrict__ Wf,
                                                 const float* __restrict__ x,
                                                 const int* __restrict__ idx,
                                                 float* __restrict__ P) {
    const int tid  = threadIdx.x;
    const int wave = tid >> 6, lane = tid & 63;

    // id = zb + 4*xb + 32*yb -> XCD (id%8) = zb+4*(xb&1), constant per window.
    const int id = blockIdx.x;
    const int zb = id & 3;
    const int xb = (id >> 2) & 7;
    const int yb = id >> 5;
    const int o0 = xb * 128, b0 = yb * 128, ibase = zb * 256;

    const char* wbase = (const char*)Wf + (size_t)(zb * 8 + xb) * 64 * 16384;
    const int   lofs  = lane * 16;

    __shared__ unsigned char sm[2][16384];     // double-buffered B slab

    const int arow = b0 + wave * 32 + (lane & 15);
    const float* xg = x + (size_t)arow * IN_SZ + ibase + (lane >> 4) * 8;
    const int*   ig = idx + (size_t)arow * IN_SZ + ibase + (lane >> 4) * 8;

    floatx4 acc[16];
#pragma unroll
    for (int i = 0; i < 16; ++i) acc[i] = (floatx4){0.f, 0.f, 0.f, 0.f};

    uint4 xr[2][2], oh[2][2];

#define RELOADA(ih)                                                           \
    {   int io_ = (ih) * 64;                                                  \
        _Pragma("unroll")                                                     \
        for (int mt_ = 0; mt_ < 2; ++mt_)                                     \
            _Pragma("unroll")                                                 \
            for (int hh_ = 0; hh_ < 2; ++hh_) {                               \
                const float* xp_ = xg + mt_ * 16 * IN_SZ + io_ + hh_ * 32;    \
                const int*   ip_ = ig + mt_ * 16 * IN_SZ + io_ + hh_ * 32;    \
                float a_[8]; int b_[8];                                       \
                *(float4*)(a_)     = *(const float4*)xp_;                     \
                *(float4*)(a_ + 4) = *((const float4*)xp_ + 1);               \
                *(int4*)(b_)       = *(const int4*)ip_;                       \
                *(int4*)(b_ + 4)   = *((const int4*)ip_ + 1);                 \
                unsigned short xv_[8];                                        \
                _Pragma("unroll")                                             \
                for (int j_ = 0; j_ < 8; ++j_) xv_[j_] = f32_to_bf16_rne(a_[j_]); \
                xr[mt_][hh_] = *(uint4*)xv_;                                  \
                uint32_t iw_[4];                                              \
                _Pragma("unroll")                                             \
                for (int w_ = 0; w_ < 4; ++w_)                                \
                    iw_[w_] = (1u << b_[2 * w_]) | ((1u << b_[2 * w_ + 1]) << 16); \
                oh[mt_][hh_] = *(uint4*)iw_;                                  \
            }                                                                 \
    }

#define MASKS(hh)                                                             \
        _Pragma("unroll")                                                     \
        for (int mt_ = 0; mt_ < 2; ++mt_) {                                   \
            aF[mt_].u.x = mask3(xr[mt_][hh].x, oh[mt_][hh].x, sh_);           \
            aF[mt_].u.y = mask3(xr[mt_][hh].y, oh[mt_][hh].y, sh_);           \
            aF[mt_].u.z = mask3(xr[mt_][hh].z, oh[mt_][hh].z, sh_);           \
            aF[mt_].u.w = mask3(xr[mt_][hh].w, oh[mt_][hh].w, sh_);           \
        }

    // each wave stages 4KB of the 16KB slab: 4 x global_load_lds(16B)
    const int soff = wave * 4096 + lofs;
#define STAGE(s_, pb_)                                                        \
    {   const char* gp_ = wbase + (size_t)(s_) * 16384 + soff;                \
        unsigned char* lp_ = &sm[pb_][soff];                                  \
        gload_lds16(gp_,        lp_);                                         \
        gload_lds16(gp_ + 1024, lp_ + 1024);                                  \
        gload_lds16(gp_ + 2048, lp_ + 2048);                                  \
        gload_lds16(gp_ + 3072, lp_ + 3072);                                  \
    }

// one slab: prefetch s+1 into buffer pn_, consume buffer pc_ (static indices)
#define SLAB(s_, pc_, pn_)                                                    \
    {   if ((s_) < 63) STAGE((s_) + 1, pn_);                                  \
        if ((s_) && (((s_) & 15) == 0)) RELOADA((s_) >> 4);                   \
        const unsigned short sh_ = (unsigned short)(15 - ((s_) & 15));        \
        union { uint4 u; short8 s8; } aF[2];                                  \
        short8 f_[8];                                                         \
        _Pragma("unroll")                                                     \
        for (int nt_ = 0; nt_ < 8; ++nt_)                                     \
            f_[nt_] = *(const short8*)&sm[pc_][nt_ * 1024 + lofs];            \
        MASKS(0);                                                             \
        _Pragma("unroll")                                                     \
        for (int mt_ = 0; mt_ < 2; ++mt_)                                     \
            _Pragma("unroll")                                                 \
            for (int nt_ = 0; nt_ < 8; ++nt_)                                 \
                acc[mt_ * 8 + nt_] = __builtin_amdgcn_mfma_f32_16x16x32_bf16( \
                    aF[mt_].s8, f_[nt_], acc[mt_ * 8 + nt_], 0, 0, 0);        \
        _Pragma("unroll")                                                     \
        for (int nt_ = 0; nt_ < 8; ++nt_)                                     \
            f_[nt_] = *(const short8*)&sm[pc_][8192 + nt_ * 1024 + lofs];     \
        MASKS(1);                                                             \
        _Pragma("unroll")                                                     \
        for (int mt_ = 0; mt_ < 2; ++mt_)                                     \
            _Pragma("unroll")                                                 \
            for (int nt_ = 0; nt_ < 8; ++nt_)                                 \
                acc[mt_ * 8 + nt_] = __builtin_amdgcn_mfma_f32_16x16x32_bf16( \
                    aF[mt_].s8, f_[nt_], acc[mt_ * 8 + nt_], 0, 0, 0);        \
        __syncthreads();                                                      \
    }

    RELOADA(0);
    STAGE(0, 0);
    __syncthreads();                           // stage(0) complete (vmcnt drain)

#pragma unroll 1
    for (int g = 0; g < 32; ++g) {
        SLAB(2 * g,     0, 1);
        SLAB(2 * g + 1, 1, 0);
    }

    // epilogue: plain stores to private partial buffer (C/D: col=lane&15 -> o,
    // row=(lane>>4)*4+e -> b). No atomics anywhere.
    float* Pz = P + (size_t)zb * (B_SZ * OUT_SZ);
    int cn = lane & 15, rq = lane >> 4;
#pragma unroll
    for (int mt = 0; mt < 2; ++mt)
#pragma unroll
        for (int nt = 0; nt < 8; ++nt) {
            int bb = b0 + wave * 32 + mt * 16 + rq * 4;
            int oo = o0 + nt * 16 + cn;
#pragma unroll
            for (int e = 0; e < 4; ++e)
                Pz[(size_t)(bb + e) * OUT_SZ + oo] = acc[mt * 8 + nt][e];
        }
#undef RELOADA
#undef MASKS
#undef STAGE
#undef SLAB
}

// ---------------- reduce: out = bias + sum_z P[z] ----------------
__global__ void k_reduce(const float* __restrict__ P, const float* __restrict__ bias,
                         float* __restrict__ out) {
    int t = blockIdx.x * 256 + threadIdx.x;    // float4 index, 524288 total
    const float4* b4 = (const float4*)bias;
    float4 a = b4[t & 255];
#pragma unroll
    for (int z = 0; z < NZB; ++z) {
        float4 v = ((const float4*)P)[(size_t)z * (B_SZ * OUT_SZ / 4) + t];
        a.x += v.x; a.y += v.y; a.z += v.z; a.w += v.w;
    }
    ((float4*)out)[t] = a;
}

// ---------------- fallback (ws too small): exact fp32 gather ----------------
__global__ void k_naive(const float* __restrict__ x, const int* __restrict__ idx,
                        const float* __restrict__ W, const float* __restrict__ bias,
                        float* __restrict__ out) {
    int b = blockIdx.x;
    int o = threadIdx.x * 4;
    float4 acc = *(const float4*)(bias + o);
    const float* xr = x + (size_t)b * IN_SZ;
    const int*   ir = idx + (size_t)b * IN_SZ;
    for (int i = 0; i < IN_SZ; ++i) {
        float xv = xr[i];
        int q = ir[i];
        float4 w4 = *(const float4*)(W + ((size_t)q * IN_SZ + i) * OUT_SZ + o);
        acc.x += xv * w4.x; acc.y += xv * w4.y;
        acc.z += xv * w4.z; acc.w += xv * w4.w;
    }
    *(float4*)(out + (size_t)b * OUT_SZ + o) = acc;
}

extern "C" void kernel_launch(void* const* d_in, const int* in_sizes, int n_in,
                              void* d_out, int out_size, void* d_ws, size_t ws_size,
                              hipStream_t stream) {
    const float* x    = (const float*)d_in[0];
    const int*   idx  = (const int*)d_in[1];
    const float* W    = (const float*)d_in[2];
    const float* bias = (const float*)d_in[3];
    float* out = (float*)d_out;

    const size_t wf_bytes = (size_t)2048 * 16384;                 // 32 MB frag-linear W
    const size_t p_bytes  = (size_t)NZB * B_SZ * OUT_SZ * 4;      // 32 MB partials
    if (ws_size < wf_bytes + p_bytes) {
        k_naive<<<dim3(B_SZ), dim3(256), 0, stream>>>(x, idx, W, bias, out);
        return;
    }
    unsigned short* Wf = (unsigned short*)d_ws;
    float* P = (float*)((char*)d_ws + wf_bytes);

    k_build_wf<<<dim3(2048), dim3(256), 0, stream>>>(W, Wf);
    k_gemm<<<dim3(NZB * 8 * (B_SZ / 128)), dim3(256), 0, stream>>>(Wf, x, idx, P);
    k_reduce<<<dim3(2048), dim3(256), 0, stream>>>(P, bias, out);
}